// Round 11
// baseline (273.920 us; speedup 1.0000x reference)
//
#include <hip/hip_runtime.h>

#define N_NODES   10000
#define C_DIM     128
#define H_DIM     8
#define YZ_TOTAL  (N_NODES * H_DIM)
#define GRID      2048
#define BLOCK     256
#define YZ_BLK    1250                         /* blocks 0..1249 produce yz */
#define NTHREADS  (GRID * BLOCK)               /* 524288 */
#define COPY_THR  ((GRID - YZ_BLK) * BLOCK)    /* 204288 idx-copy threads */
#define SPIN_LIMIT 400000

typedef _Float16 h2 __attribute__((ext_vector_type(2)));
typedef _Float16 h8 __attribute__((ext_vector_type(8)));

// Barrier state in device globals (zero at load; reset by last block out).
__device__ int g_done = 0;
__device__ int g_exit = 0;

__device__ __forceinline__ float sigmoid_fast(float v) {
    return __builtin_amdgcn_rcpf(1.f + __expf(-v));   // absmax-safe (R1/R8 precedent)
}

// Fallback if barrier times out: exact f32 compute from x (never taken normally).
__device__ __noinline__ void direct_edge(const float* __restrict__ x,
                                         const float* __restrict__ W,
                                         const float* __restrict__ b,
                                         int r, int c, float a,
                                         float* __restrict__ outp) {
    float acc[H_DIM];
#pragma unroll
    for (int h = 0; h < H_DIM; ++h) acc[h] = b[h];
    const float* xr = x + (size_t)r * C_DIM;
    const float* xc = x + (size_t)c * C_DIM;
    for (int k = 0; k < C_DIM; ++k) {
        float va = xr[k], vb = xc[k];
#pragma unroll
        for (int h = 0; h < H_DIM; ++h) {
            acc[h] = fmaf(va, W[k * H_DIM + h], acc[h]);
            acc[h] = fmaf(vb, W[(C_DIM + k) * H_DIM + h], acc[h]);
        }
    }
    const bool self = (r == c);
#pragma unroll
    for (int h = 0; h < H_DIM; ++h) {
        float s = 1.f / (1.f + __expf(-acc[h]));
        outp[h] = self ? 1.f : s * a;
    }
}

extern "C" __global__ void __launch_bounds__(BLOCK, 8)
fused_attn(const float* __restrict__ x,  const int* __restrict__ ei,
           const float* __restrict__ ea, const float* __restrict__ W,
           const float* __restrict__ b,  float* __restrict__ out,
           _Float16* __restrict__ yzh, int E) {
    const int tid = threadIdx.x;
    const int bid = blockIdx.x;
    const size_t ib = (size_t)E * H_DIM;

    if (bid < YZ_BLK) {
        // ---- Phase 1a (blocks 0..1249): yz tables, 32 thr/node (R8 body) ----
        const int t = bid * BLOCK + tid;          // [0, 320000) exactly
        const int n = t >> 5;
        const int w  = t & 31;
        const int s  = w >> 2;
        const int hp = w & 3;
        const int h0 = hp * 2;

        const float4* xr4 = (const float4*)(x + (size_t)n * C_DIM) + s * 4;
        float4 xv0 = xr4[0], xv1 = xr4[1], xv2 = xr4[2], xv3 = xr4[3];
        const float xk[16] = { xv0.x,xv0.y,xv0.z,xv0.w, xv1.x,xv1.y,xv1.z,xv1.w,
                               xv2.x,xv2.y,xv2.z,xv2.w, xv3.x,xv3.y,xv3.z,xv3.w };

        const int k0 = s * 16;
        const float* wr = W + (size_t)k0 * H_DIM + h0;
        const float* wc = W + (size_t)(C_DIM + k0) * H_DIM + h0;

        float ar0 = 0.f, ar1 = 0.f, ac0 = 0.f, ac1 = 0.f;
#pragma unroll
        for (int j = 0; j < 16; ++j) {
            float2 wr2 = *(const float2*)(wr + j * H_DIM);
            float2 wc2 = *(const float2*)(wc + j * H_DIM);
            ar0 = fmaf(xk[j], wr2.x, ar0);
            ar1 = fmaf(xk[j], wr2.y, ar1);
            ac0 = fmaf(xk[j], wc2.x, ac0);
            ac1 = fmaf(xk[j], wc2.y, ac1);
        }
#pragma unroll
        for (int m = 4; m <= 16; m <<= 1) {
            ar0 += __shfl_xor(ar0, m, 64);
            ar1 += __shfl_xor(ar1, m, 64);
            ac0 += __shfl_xor(ac0, m, 64);
            ac1 += __shfl_xor(ac1, m, 64);
        }
        if (s == 0) {
            float2 bb = *(const float2*)(b + h0);
            h2 yv = { (_Float16)(ar0 + bb.x), (_Float16)(ar1 + bb.y) };
            h2 zv = { (_Float16)ac0,          (_Float16)ac1 };
            *(h2*)(yzh + (size_t)n * H_DIM + h0)            = yv;
            *(h2*)(yzh + YZ_TOTAL + (size_t)n * H_DIM + h0) = zv;
        }
        // Release: block's yzh stores (only ~0.25 KB dirty/block) then signal.
        __syncthreads();
        if (tid == 0)
            __hip_atomic_fetch_add(&g_done, 1, __ATOMIC_RELEASE,
                                   __HIP_MEMORY_SCOPE_AGENT);
    } else {
        // ---- Phase 1b (blocks 1250..2047): idx pass-through, overlaps yz ----
        const int j = (bid - YZ_BLK) * BLOCK + tid;
        const int nchunks = (2 * E + 3) / 4;               // 320000
        for (int ch = j; ch < nchunks; ch += COPY_THR) {
            const int i = ch * 4;
            if (i + 3 < 2 * E) {
                int4 v = *(const int4*)(ei + i);
                *(float4*)(out + ib + i) =
                    make_float4((float)v.x, (float)v.y, (float)v.z, (float)v.w);
            } else {
                for (int q = i; q < 2 * E; ++q) out[ib + q] = (float)ei[q];
            }
        }
    }

    // ---- Barrier: RELAXED polls (no per-poll invalidate — R1's fatal flaw) ----
    __shared__ int s_to;
    if (tid == 0) {
        int spins = 0, to = 0;
        while (__hip_atomic_load(&g_done, __ATOMIC_RELAXED,
                                 __HIP_MEMORY_SCOPE_AGENT) < YZ_BLK) {
            __builtin_amdgcn_s_sleep(4);
            if (++spins > SPIN_LIMIT) { to = 1; break; }
        }
        s_to = to;
    }
    __syncthreads();
    __builtin_amdgcn_fence(__ATOMIC_ACQUIRE, "agent");   // one inv, after exit
    const bool timeout = (s_to != 0);

    // ---- Phase 2: all 524288 threads grid-stride the edges (R9 K2 body) ----
    for (int e = bid * BLOCK + tid; e < E; e += NTHREADS) {
        int r = ei[e];
        int c = ei[E + e];
        float a = ea[e];
        float* outp = out + (size_t)e * H_DIM;
        if (!timeout) {
            h8 yv = *(const h8*)(yzh + (size_t)r * H_DIM);
            h8 zv = *(const h8*)(yzh + YZ_TOTAL + (size_t)c * H_DIM);
            const bool self = (r == c);
            float res[8];
#pragma unroll
            for (int h = 0; h < 8; ++h) {
                float v = (float)yv[h] + (float)zv[h];
                res[h] = self ? 1.f : sigmoid_fast(v) * a;
            }
            float4* op = (float4*)outp;
            op[0] = make_float4(res[0], res[1], res[2], res[3]);
            op[1] = make_float4(res[4], res[5], res[6], res[7]);
        } else {
            direct_edge(x, W, b, r, c, a, outp);
        }
    }

    // ---- Reset barrier state for the next graph replay ----
    __syncthreads();
    if (tid == 0) {
        int v = __hip_atomic_fetch_add(&g_exit, 1, __ATOMIC_ACQ_REL,
                                       __HIP_MEMORY_SCOPE_AGENT);
        if (v == GRID - 1) {
            __hip_atomic_store(&g_done, 0, __ATOMIC_RELAXED, __HIP_MEMORY_SCOPE_AGENT);
            __hip_atomic_store(&g_exit, 0, __ATOMIC_RELAXED, __HIP_MEMORY_SCOPE_AGENT);
        }
    }
}

extern "C" void kernel_launch(void* const* d_in, const int* in_sizes, int n_in,
                              void* d_out, int out_size, void* d_ws, size_t ws_size,
                              hipStream_t stream) {
    const float* x  = (const float*)d_in[0];
    const int*   ei = (const int*)d_in[1];   // int32 on device per harness convention
    const float* ea = (const float*)d_in[2];
    const float* W  = (const float*)d_in[3];
    const float* b  = (const float*)d_in[4];
    float* out = (float*)d_out;
    _Float16* yzh = (_Float16*)d_ws;         // 2*N*H*2 = 320 KB
    const int E = in_sizes[2];               // 640000

    hipLaunchKernelGGL(fused_attn, dim3(GRID), dim3(BLOCK), 0, stream,
                       x, ei, ea, W, b, out, yzh, E);
}

// Round 12
// 31.242 us; speedup vs baseline: 8.7677x; 8.7677x over previous
//
#include <hip/hip_runtime.h>

#define N_NODES   10000
#define C_DIM     128
#define H_DIM     8
#define YZ_TOTAL  (N_NODES * H_DIM)
#define YZ_BLOCKS ((N_NODES * 32) / 256)     /* 1250 */

// clang-native f16 vectors (single dwordx4 gather per node row)
typedef _Float16 h2 __attribute__((ext_vector_type(2)));
typedef _Float16 h8 __attribute__((ext_vector_type(8)));

// ---------------------------------------------------------------------------
// K1: identical to R9 (yz tables + idx pass-through in trailing blocks).
// Idempotent => launched twice as a timing probe (PROBE: dur-23.6 = warmK1+OH).
// ---------------------------------------------------------------------------
__global__ void __launch_bounds__(256)
k1_yz_and_index(const float* __restrict__ x, const float* __restrict__ W,
                const float* __restrict__ b, const int* __restrict__ ei,
                float* __restrict__ out, _Float16* __restrict__ yzh, int E) {
    const int bid = blockIdx.x;

    if (bid < YZ_BLOCKS) {
        const int t = bid * 256 + threadIdx.x;
        const int n = t >> 5;
        if (n >= N_NODES) return;
        const int w  = t & 31;
        const int s  = w >> 2;
        const int hp = w & 3;
        const int h0 = hp * 2;

        const float4* xr4 = (const float4*)(x + (size_t)n * C_DIM) + s * 4;
        float4 xv0 = xr4[0], xv1 = xr4[1], xv2 = xr4[2], xv3 = xr4[3];
        const float xk[16] = { xv0.x,xv0.y,xv0.z,xv0.w, xv1.x,xv1.y,xv1.z,xv1.w,
                               xv2.x,xv2.y,xv2.z,xv2.w, xv3.x,xv3.y,xv3.z,xv3.w };

        const int k0 = s * 16;
        const float* wr = W + (size_t)k0 * H_DIM + h0;
        const float* wc = W + (size_t)(C_DIM + k0) * H_DIM + h0;

        float ar0 = 0.f, ar1 = 0.f, ac0 = 0.f, ac1 = 0.f;
#pragma unroll
        for (int j = 0; j < 16; ++j) {
            float2 wr2 = *(const float2*)(wr + j * H_DIM);
            float2 wc2 = *(const float2*)(wc + j * H_DIM);
            ar0 = fmaf(xk[j], wr2.x, ar0);
            ar1 = fmaf(xk[j], wr2.y, ar1);
            ac0 = fmaf(xk[j], wc2.x, ac0);
            ac1 = fmaf(xk[j], wc2.y, ac1);
        }
#pragma unroll
        for (int m = 4; m <= 16; m <<= 1) {
            ar0 += __shfl_xor(ar0, m, 64);
            ar1 += __shfl_xor(ar1, m, 64);
            ac0 += __shfl_xor(ac0, m, 64);
            ac1 += __shfl_xor(ac1, m, 64);
        }
        if (s == 0) {
            float2 bb = *(const float2*)(b + h0);
            h2 yv = { (_Float16)(ar0 + bb.x), (_Float16)(ar1 + bb.y) };
            h2 zv = { (_Float16)ac0,          (_Float16)ac1 };
            *(h2*)(yzh + (size_t)n * H_DIM + h0)            = yv;
            *(h2*)(yzh + YZ_TOTAL + (size_t)n * H_DIM + h0) = zv;
        }
    } else {
        const size_t ib = (size_t)E * H_DIM;
        const int t = (bid - YZ_BLOCKS) * 256 + threadIdx.x;
        const int i = t * 4;
        const int total = 2 * E;
        if (i + 3 < total) {
            int4 v = *(const int4*)(ei + i);
            *(float4*)(out + ib + i) =
                make_float4((float)v.x, (float)v.y, (float)v.z, (float)v.w);
        } else {
            for (int j = i; j < total; ++j) out[ib + j] = (float)ei[j];
        }
    }
}

// ---------------------------------------------------------------------------
// K2: identical to R9.
// ---------------------------------------------------------------------------
__device__ __forceinline__ float sigmoid_fast(float v) {
    return __builtin_amdgcn_rcpf(1.f + __expf(-v));
}

__global__ void edge_alpha(const int* __restrict__ ei,
                           const float* __restrict__ ea,
                           const _Float16* __restrict__ yzh,
                           float* __restrict__ out, int E) {
    const int e = blockIdx.x * blockDim.x + threadIdx.x;
    if (e >= E) return;
    int r = ei[e];
    int c = ei[E + e];
    float a = ea[e];

    h8 yv = *(const h8*)(yzh + (size_t)r * H_DIM);
    h8 zv = *(const h8*)(yzh + YZ_TOTAL + (size_t)c * H_DIM);

    const bool self = (r == c);
    float res[8];
#pragma unroll
    for (int h = 0; h < 8; ++h) {
        float v = (float)yv[h] + (float)zv[h];
        res[h] = self ? 1.f : sigmoid_fast(v) * a;
    }

    float4* op = (float4*)(out + (size_t)e * H_DIM);
    op[0] = make_float4(res[0], res[1], res[2], res[3]);
    op[1] = make_float4(res[4], res[5], res[6], res[7]);
}

extern "C" void kernel_launch(void* const* d_in, const int* in_sizes, int n_in,
                              void* d_out, int out_size, void* d_ws, size_t ws_size,
                              hipStream_t stream) {
    const float* x  = (const float*)d_in[0];
    const int*   ei = (const int*)d_in[1];   // int32 on device per harness convention
    const float* ea = (const float*)d_in[2];
    const float* W  = (const float*)d_in[3];
    const float* b  = (const float*)d_in[4];
    float* out = (float*)d_out;
    _Float16* yzh = (_Float16*)d_ws;         // 2*N*H*2 = 320 KB
    const int E = in_sizes[2];               // 640000

    {
        const int conv_threads = (2 * E + 3) / 4;                // 320000
        const int conv_blocks  = (conv_threads + 255) / 256;     // 1250
        const int grid = YZ_BLOCKS + conv_blocks;                // 2500
        // PROBE: K1 launched twice (idempotent). dur - 23.6 = warm-K1 + OH.
        hipLaunchKernelGGL(k1_yz_and_index, dim3(grid), dim3(256), 0, stream,
                           x, W, b, ei, out, yzh, E);
        hipLaunchKernelGGL(k1_yz_and_index, dim3(grid), dim3(256), 0, stream,
                           x, W, b, ei, out, yzh, E);
    }
    {
        const int grid = (E + 255) / 256;                        // 2500
        hipLaunchKernelGGL(edge_alpha, dim3(grid), dim3(256), 0, stream,
                           ei, ea, yzh, out, E);
    }
}

// Round 13
// 23.671 us; speedup vs baseline: 11.5719x; 1.3198x over previous
//
#include <hip/hip_runtime.h>

#define N_NODES   10000
#define C_DIM     128
#define H_DIM     8
#define YZ_TOTAL  (N_NODES * H_DIM)
#define YZ_BLOCKS ((N_NODES * 32) / 256)     /* 1250 */

// clang-native vector types
typedef _Float16 h2 __attribute__((ext_vector_type(2)));
typedef _Float16 h8 __attribute__((ext_vector_type(8)));
typedef float    fx4 __attribute__((ext_vector_type(4)));

// ---------------------------------------------------------------------------
// K1: identical to R9 except the idx pass-through uses NON-TEMPORAL stores.
// That 10.2 MB is write-once, never re-read by a kernel: keeping it out of
// L2 shrinks the serial dirty-writeback at the K1->K2 dispatch boundary.
// ---------------------------------------------------------------------------
__global__ void __launch_bounds__(256)
k1_yz_and_index(const float* __restrict__ x, const float* __restrict__ W,
                const float* __restrict__ b, const int* __restrict__ ei,
                float* __restrict__ out, _Float16* __restrict__ yzh, int E) {
    const int bid = blockIdx.x;

    if (bid < YZ_BLOCKS) {
        const int t = bid * 256 + threadIdx.x;
        const int n = t >> 5;
        if (n >= N_NODES) return;
        const int w  = t & 31;
        const int s  = w >> 2;
        const int hp = w & 3;
        const int h0 = hp * 2;

        const float4* xr4 = (const float4*)(x + (size_t)n * C_DIM) + s * 4;
        float4 xv0 = xr4[0], xv1 = xr4[1], xv2 = xr4[2], xv3 = xr4[3];
        const float xk[16] = { xv0.x,xv0.y,xv0.z,xv0.w, xv1.x,xv1.y,xv1.z,xv1.w,
                               xv2.x,xv2.y,xv2.z,xv2.w, xv3.x,xv3.y,xv3.z,xv3.w };

        const int k0 = s * 16;
        const float* wr = W + (size_t)k0 * H_DIM + h0;
        const float* wc = W + (size_t)(C_DIM + k0) * H_DIM + h0;

        float ar0 = 0.f, ar1 = 0.f, ac0 = 0.f, ac1 = 0.f;
#pragma unroll
        for (int j = 0; j < 16; ++j) {
            float2 wr2 = *(const float2*)(wr + j * H_DIM);
            float2 wc2 = *(const float2*)(wc + j * H_DIM);
            ar0 = fmaf(xk[j], wr2.x, ar0);
            ar1 = fmaf(xk[j], wr2.y, ar1);
            ac0 = fmaf(xk[j], wc2.x, ac0);
            ac1 = fmaf(xk[j], wc2.y, ac1);
        }
#pragma unroll
        for (int m = 4; m <= 16; m <<= 1) {
            ar0 += __shfl_xor(ar0, m, 64);
            ar1 += __shfl_xor(ar1, m, 64);
            ac0 += __shfl_xor(ac0, m, 64);
            ac1 += __shfl_xor(ac1, m, 64);
        }
        if (s == 0) {
            float2 bb = *(const float2*)(b + h0);
            h2 yv = { (_Float16)(ar0 + bb.x), (_Float16)(ar1 + bb.y) };
            h2 zv = { (_Float16)ac0,          (_Float16)ac1 };
            *(h2*)(yzh + (size_t)n * H_DIM + h0)            = yv;
            *(h2*)(yzh + YZ_TOTAL + (size_t)n * H_DIM + h0) = zv;
        }
    } else {
        const size_t ib = (size_t)E * H_DIM;
        const int t = (bid - YZ_BLOCKS) * 256 + threadIdx.x;
        const int i = t * 4;
        const int total = 2 * E;
        if (i + 3 < total) {
            int4 v = *(const int4*)(ei + i);
            fx4 f = { (float)v.x, (float)v.y, (float)v.z, (float)v.w };
            __builtin_nontemporal_store(f, (fx4*)(out + ib + i));   // bypass L2
        } else {
            for (int j = i; j < total; ++j) out[ib + j] = (float)ei[j];
        }
    }
}

// ---------------------------------------------------------------------------
// K2: identical to R9.
// ---------------------------------------------------------------------------
__device__ __forceinline__ float sigmoid_fast(float v) {
    return __builtin_amdgcn_rcpf(1.f + __expf(-v));
}

__global__ void edge_alpha(const int* __restrict__ ei,
                           const float* __restrict__ ea,
                           const _Float16* __restrict__ yzh,
                           float* __restrict__ out, int E) {
    const int e = blockIdx.x * blockDim.x + threadIdx.x;
    if (e >= E) return;
    int r = ei[e];
    int c = ei[E + e];
    float a = ea[e];

    h8 yv = *(const h8*)(yzh + (size_t)r * H_DIM);
    h8 zv = *(const h8*)(yzh + YZ_TOTAL + (size_t)c * H_DIM);

    const bool self = (r == c);
    float res[8];
#pragma unroll
    for (int h = 0; h < 8; ++h) {
        float v = (float)yv[h] + (float)zv[h];
        res[h] = self ? 1.f : sigmoid_fast(v) * a;
    }

    float4* op = (float4*)(out + (size_t)e * H_DIM);
    op[0] = make_float4(res[0], res[1], res[2], res[3]);
    op[1] = make_float4(res[4], res[5], res[6], res[7]);
}

extern "C" void kernel_launch(void* const* d_in, const int* in_sizes, int n_in,
                              void* d_out, int out_size, void* d_ws, size_t ws_size,
                              hipStream_t stream) {
    const float* x  = (const float*)d_in[0];
    const int*   ei = (const int*)d_in[1];   // int32 on device per harness convention
    const float* ea = (const float*)d_in[2];
    const float* W  = (const float*)d_in[3];
    const float* b  = (const float*)d_in[4];
    float* out = (float*)d_out;
    _Float16* yzh = (_Float16*)d_ws;         // 2*N*H*2 = 320 KB
    const int E = in_sizes[2];               // 640000

    {
        const int conv_threads = (2 * E + 3) / 4;                // 320000
        const int conv_blocks  = (conv_threads + 255) / 256;     // 1250
        const int grid = YZ_BLOCKS + conv_blocks;                // 2500
        hipLaunchKernelGGL(k1_yz_and_index, dim3(grid), dim3(256), 0, stream,
                           x, W, b, ei, out, yzh, E);
    }
    {
        const int grid = (E + 255) / 256;                        // 2500
        hipLaunchKernelGGL(edge_alpha, dim3(grid), dim3(256), 0, stream,
                           ei, ea, yzh, out, E);
    }
}

// Round 14
// 22.338 us; speedup vs baseline: 12.2627x; 1.0597x over previous
//
#include <hip/hip_runtime.h>

#define N_NODES   10000
#define C_DIM     128
#define H_DIM     8
#define YZ_TOTAL  (N_NODES * H_DIM)
#define YZ_BLOCKS ((N_NODES * 32) / 256)     /* 1250 */

// clang-native vector types
typedef _Float16 h2 __attribute__((ext_vector_type(2)));
typedef _Float16 h8 __attribute__((ext_vector_type(8)));
typedef float    fx4 __attribute__((ext_vector_type(4)));

// ---------------------------------------------------------------------------
// K1: identical to R13 (yz tables f16 + NT idx pass-through).
// ---------------------------------------------------------------------------
__global__ void __launch_bounds__(256)
k1_yz_and_index(const float* __restrict__ x, const float* __restrict__ W,
                const float* __restrict__ b, const int* __restrict__ ei,
                float* __restrict__ out, _Float16* __restrict__ yzh, int E) {
    const int bid = blockIdx.x;

    if (bid < YZ_BLOCKS) {
        const int t = bid * 256 + threadIdx.x;
        const int n = t >> 5;
        if (n >= N_NODES) return;
        const int w  = t & 31;
        const int s  = w >> 2;
        const int hp = w & 3;
        const int h0 = hp * 2;

        const float4* xr4 = (const float4*)(x + (size_t)n * C_DIM) + s * 4;
        float4 xv0 = xr4[0], xv1 = xr4[1], xv2 = xr4[2], xv3 = xr4[3];
        const float xk[16] = { xv0.x,xv0.y,xv0.z,xv0.w, xv1.x,xv1.y,xv1.z,xv1.w,
                               xv2.x,xv2.y,xv2.z,xv2.w, xv3.x,xv3.y,xv3.z,xv3.w };

        const int k0 = s * 16;
        const float* wr = W + (size_t)k0 * H_DIM + h0;
        const float* wc = W + (size_t)(C_DIM + k0) * H_DIM + h0;

        float ar0 = 0.f, ar1 = 0.f, ac0 = 0.f, ac1 = 0.f;
#pragma unroll
        for (int j = 0; j < 16; ++j) {
            float2 wr2 = *(const float2*)(wr + j * H_DIM);
            float2 wc2 = *(const float2*)(wc + j * H_DIM);
            ar0 = fmaf(xk[j], wr2.x, ar0);
            ar1 = fmaf(xk[j], wr2.y, ar1);
            ac0 = fmaf(xk[j], wc2.x, ac0);
            ac1 = fmaf(xk[j], wc2.y, ac1);
        }
#pragma unroll
        for (int m = 4; m <= 16; m <<= 1) {
            ar0 += __shfl_xor(ar0, m, 64);
            ar1 += __shfl_xor(ar1, m, 64);
            ac0 += __shfl_xor(ac0, m, 64);
            ac1 += __shfl_xor(ac1, m, 64);
        }
        if (s == 0) {
            float2 bb = *(const float2*)(b + h0);
            h2 yv = { (_Float16)(ar0 + bb.x), (_Float16)(ar1 + bb.y) };
            h2 zv = { (_Float16)ac0,          (_Float16)ac1 };
            *(h2*)(yzh + (size_t)n * H_DIM + h0)            = yv;
            *(h2*)(yzh + YZ_TOTAL + (size_t)n * H_DIM + h0) = zv;
        }
    } else {
        const size_t ib = (size_t)E * H_DIM;
        const int t = (bid - YZ_BLOCKS) * 256 + threadIdx.x;
        const int i = t * 4;
        const int total = 2 * E;
        if (i + 3 < total) {
            int4 v = *(const int4*)(ei + i);
            fx4 f = { (float)v.x, (float)v.y, (float)v.z, (float)v.w };
            __builtin_nontemporal_store(f, (fx4*)(out + ib + i));
        } else {
            for (int j = i; j < total; ++j) out[ib + j] = (float)ei[j];
        }
    }
}

// ---------------------------------------------------------------------------
// K2: R9 body; streams (ei, ea) via NT loads, alpha via NT stores.
// Gathers (yzh) stay normally-cached => table keeps L2 residency.
// ---------------------------------------------------------------------------
__device__ __forceinline__ float sigmoid_fast(float v) {
    return __builtin_amdgcn_rcpf(1.f + __expf(-v));
}

__global__ void edge_alpha(const int* __restrict__ ei,
                           const float* __restrict__ ea,
                           const _Float16* __restrict__ yzh,
                           float* __restrict__ out, int E) {
    const int e = blockIdx.x * blockDim.x + threadIdx.x;
    if (e >= E) return;
    int   r = __builtin_nontemporal_load(ei + e);        // stream: no L2 alloc
    int   c = __builtin_nontemporal_load(ei + E + e);
    float a = __builtin_nontemporal_load(ea + e);

    h8 yv = *(const h8*)(yzh + (size_t)r * H_DIM);       // cached gather
    h8 zv = *(const h8*)(yzh + YZ_TOTAL + (size_t)c * H_DIM);

    const bool self = (r == c);
    float res[8];
#pragma unroll
    for (int h = 0; h < 8; ++h) {
        float v = (float)yv[h] + (float)zv[h];
        res[h] = self ? 1.f : sigmoid_fast(v) * a;
    }

    fx4 lo = { res[0], res[1], res[2], res[3] };
    fx4 hi = { res[4], res[5], res[6], res[7] };
    __builtin_nontemporal_store(lo, (fx4*)(out + (size_t)e * H_DIM));
    __builtin_nontemporal_store(hi, (fx4*)(out + (size_t)e * H_DIM + 4));
}

extern "C" void kernel_launch(void* const* d_in, const int* in_sizes, int n_in,
                              void* d_out, int out_size, void* d_ws, size_t ws_size,
                              hipStream_t stream) {
    const float* x  = (const float*)d_in[0];
    const int*   ei = (const int*)d_in[1];   // int32 on device per harness convention
    const float* ea = (const float*)d_in[2];
    const float* W  = (const float*)d_in[3];
    const float* b  = (const float*)d_in[4];
    float* out = (float*)d_out;
    _Float16* yzh = (_Float16*)d_ws;         // 2*N*H*2 = 320 KB
    const int E = in_sizes[2];               // 640000

    {
        const int conv_threads = (2 * E + 3) / 4;                // 320000
        const int conv_blocks  = (conv_threads + 255) / 256;     // 1250
        const int grid = YZ_BLOCKS + conv_blocks;                // 2500
        hipLaunchKernelGGL(k1_yz_and_index, dim3(grid), dim3(256), 0, stream,
                           x, W, b, ei, out, yzh, E);
    }
    {
        const int grid = (E + 255) / 256;                        // 2500
        hipLaunchKernelGGL(edge_alpha, dim3(grid), dim3(256), 0, stream,
                           ei, ea, yzh, out, E);
    }
}